// Round 15
// baseline (251.412 us; speedup 1.0000x reference)
//
#include <hip/hip_runtime.h>
#include <hip/hip_bf16.h>
#include <math.h>

// Problem constants (B=4, S=2048, Hd=1024, h=16, d=64). fp32 in/out per the
// reference; bf16 internally (MFMA) with fp32 accumulation.
#define B_SZ   4
#define S_LEN  2048
#define HD     1024
#define NHEAD  16
#define DHEAD  64
#define N3     3072          // 3*Hd
#define M_ROWS 8192          // B*S

typedef __bf16 bf16_t;
typedef __bf16 bf16x4 __attribute__((ext_vector_type(4)));
typedef __bf16 bf16x8 __attribute__((ext_vector_type(8)));
typedef float  floatx4 __attribute__((ext_vector_type(4)));

__device__ __forceinline__ float bf2f(bf16_t x) { return (float)x; }
__device__ __forceinline__ bf16_t f2bf(float f) { return (bf16_t)f; }  // RNE fptrunc
__device__ __forceinline__ float fexp2(float x) { return __builtin_amdgcn_exp2f(x); }

#define QKSCALE 0.1803368801111204f   // 0.125 * log2(e), folded into K in k1

__device__ __forceinline__ bf16x8 cvt8(const float4 lo, const float4 hi) {
    bf16x8 r;
    r[0] = (bf16_t)lo.x; r[1] = (bf16_t)lo.y; r[2] = (bf16_t)lo.z; r[3] = (bf16_t)lo.w;
    r[4] = (bf16_t)hi.x; r[5] = (bf16_t)hi.y; r[6] = (bf16_t)hi.z; r[7] = (bf16_t)hi.w;
    return r;
}

// async 16B global -> LDS (dest = wave-uniform base + lane*16)
__device__ __forceinline__ void gload_lds16(const bf16_t* g, bf16_t* l) {
    __builtin_amdgcn_global_load_lds(
        (const __attribute__((address_space(1))) void*)g,
        (__attribute__((address_space(3))) void*)l, 16, 0, 0);
}

// ---------------------------------------------------------------------------
// Kernel 0: one-shot fp32 -> bf16 convert of X and W (GEMM stages with
// global_load_lds, which can't convert dtypes). Scratch lives in the OUT
// buffer (23.1 MB <= 33.5 MB); out is only truly written by the attn kernel.
// ---------------------------------------------------------------------------
#define NXELEM (M_ROWS * HD)      // 8388608
#define NWELEM (N3 * HD)          // 3145728

__global__ __launch_bounds__(256)
void cvt_kernel(const float* __restrict__ X, const float* __restrict__ W,
                bf16_t* __restrict__ Xb, bf16_t* __restrict__ Wb)
{
    const size_t i = ((size_t)blockIdx.x * 256 + threadIdx.x) * 8;
    if (i < (size_t)NXELEM) {
        float4 lo = *(const float4*)(X + i);
        float4 hi = *(const float4*)(X + i + 4);
        *(bf16x8*)(Xb + i) = cvt8(lo, hi);
    }
    if (i < (size_t)NWELEM) {
        float4 lo = *(const float4*)(W + i);
        float4 hi = *(const float4*)(W + i + 4);
        *(bf16x8*)(Wb + i) = cvt8(lo, hi);
    }
}

// ---------------------------------------------------------------------------
// Kernel 1: bf16 GEMM qkv = Xb @ Wb^T + b. Counted-vmcnt pipeline
// (r10-verified): 3 LDS buffers, 2-deep prefetch, raw s_barrier +
// `s_waitcnt vmcnt(4) lgkmcnt(0)`. Epilogue sincos recurrence (r11).
// Round-15 change: XCD BAND-SWIZZLE (T1). Default mapping (24%8==0) pins
// XCD = hx%8, so the 24 blocks sharing an X-panel scatter over all 8 XCDs
// -> every X panel fills 8 private L2s (~128 MB L3->L2 for X vs 16 ideal).
// Remap (bijective): band = hx&7 (=XCD), idx = hy*3 + (hx>>3);
// by = band*8 + (idx&7), bx = idx>>3. Each XCD owns an 8-row by-band
// (8 X panels = 2 MB, L2-resident, fetched once) and iterates by-fast so
// each W panel gets 8 back-to-back reuses.
// ---------------------------------------------------------------------------
__global__ __launch_bounds__(256, 3)
void qkv_gemm_kernel(const bf16_t* __restrict__ Xb, const bf16_t* __restrict__ Wb,
                     const float* __restrict__ bias,
                     bf16_t* __restrict__ qws, bf16_t* __restrict__ kws,
                     bf16_t* __restrict__ vws)
{
    __shared__ bf16_t As[3][128 * 32];   // 3 x 8 KB, [row][32] bf16, linear
    __shared__ bf16_t Bs[3][128 * 32];   // 3 x 8 KB

    const int tid  = threadIdx.x;
    const int wave = tid >> 6;
    const int lane = tid & 63;
    const int l15  = lane & 15;
    const int quad = lane >> 4;
    const int wm   = wave >> 1;
    const int wn   = wave & 1;

    // XCD band swizzle (see header comment). hw linear id = hy*24+hx,
    // XCD = id%8 = hx%8 = band.
    const int band = blockIdx.x & 7;
    const int idx  = blockIdx.y * 3 + (blockIdx.x >> 3);   // 0..191
    const int m0   = (band * 8 + (idx & 7)) * 128;         // by*128
    const int n0   = (idx >> 3) * 128;                     // bx*128

    const int rowL = wave * 32 + (lane >> 2);   // + t*16
    const int colL = (lane & 3) * 8;
    const bf16_t* gA = Xb + (size_t)(m0 + rowL) * HD + colL;
    const bf16_t* gB = Wb + (size_t)(n0 + rowL) * HD + colL;
    const int lofs = wave * 1024;               // elems; +512 for t=1

    floatx4 acc[4][4];
#pragma unroll
    for (int i = 0; i < 4; ++i)
#pragma unroll
        for (int j = 0; j < 4; ++j)
            acc[i][j] = (floatx4){0.f, 0.f, 0.f, 0.f};

    // prologue: stage tile 0 -> buf0, tile 1 -> buf1; wait own tile0
    // (vmcnt(4): only tile1's 4 may remain) then raw barrier.
    gload_lds16(gA,                &As[0][0] + lofs);
    gload_lds16(gA + 16 * HD,      &As[0][0] + lofs + 512);
    gload_lds16(gB,                &Bs[0][0] + lofs);
    gload_lds16(gB + 16 * HD,      &Bs[0][0] + lofs + 512);
    gload_lds16(gA + 32,           &As[1][0] + lofs);
    gload_lds16(gA + 32 + 16 * HD, &As[1][0] + lofs + 512);
    gload_lds16(gB + 32,           &Bs[1][0] + lofs);
    gload_lds16(gB + 32 + 16 * HD, &Bs[1][0] + lofs + 512);
    asm volatile("s_waitcnt vmcnt(4)" ::: "memory");
    __builtin_amdgcn_s_barrier();

    int cur = 0, nx2 = 2;                       // buf of tile kt / tile kt+2
    for (int kt = 0; kt < 32; ++kt) {
        // issue stage of tile kt+2 (2-deep): loads stay in flight across
        // this iteration's end-of-iter wait.
        if (kt + 2 < 32) {
            const int k2 = (kt + 2) * 32;
            gload_lds16(gA + k2,           &As[nx2][0] + lofs);
            gload_lds16(gA + k2 + 16 * HD, &As[nx2][0] + lofs + 512);
            gload_lds16(gB + k2,           &Bs[nx2][0] + lofs);
            gload_lds16(gB + k2 + 16 * HD, &Bs[nx2][0] + lofs + 512);
        }

        bf16x8 af[4], bfr[4];
#pragma unroll
        for (int t = 0; t < 4; ++t) {
            af[t]  = *(const bf16x8*)(&As[cur][0] + (wm * 64 + t * 16 + l15) * 32 + quad * 8);
            bfr[t] = *(const bf16x8*)(&Bs[cur][0] + (wn * 64 + t * 16 + l15) * 32 + quad * 8);
        }
#pragma unroll
        for (int i = 0; i < 4; ++i)
#pragma unroll
            for (int j = 0; j < 4; ++j)
                acc[i][j] = __builtin_amdgcn_mfma_f32_16x16x32_bf16(
                    af[i], bfr[j], acc[i][j], 0, 0, 0);

        // end-of-iter: own tile kt+1 loads done (vmcnt(4): tile kt+2's may
        // remain) + own ds_reads done (lgkmcnt(0)). Raw barrier: no drain.
        if (kt < 30) {
            asm volatile("s_waitcnt vmcnt(4) lgkmcnt(0)" ::: "memory");
            __builtin_amdgcn_s_barrier();
        } else if (kt == 30) {
            asm volatile("s_waitcnt vmcnt(0) lgkmcnt(0)" ::: "memory");
            __builtin_amdgcn_s_barrier();
        }
        cur = (cur == 2) ? 0 : cur + 1;
        nx2 = (nx2 == 2) ? 0 : nx2 + 1;
    }

    // Epilogue: bias + RoPE + scatter. C/D: col=lane&15, row=quad*4+reg.
#pragma unroll
    for (int i = 0; i < 4; ++i) {
        const int mrow_base = m0 + wm * 64 + i * 16 + quad * 4;
        const int bb = mrow_base >> 11;
        const int sb = mrow_base & (S_LEN - 1);
#pragma unroll
        for (int j = 0; j < 2; ++j) {
            const int n1 = n0 + wn * 64 + j * 16 + l15;    // dim in [0,32)
            const int n2 = n1 + 32;
            const float b1 = bias[n1];
            const float b2 = bias[n2];
            const int which = n1 >> 10;          // 0=q 1=k 2=v (block-uniform)
            const int hd    = n1 & 1023;
            const int head  = hd >> 6;
            const int dim   = hd & 63;           // < 32 by construction
            if (which == 2) {
                // V: no RoPE; write transposed [b][h][d][s], bf16x4 over r.
                bf16x4 v1, v2;
#pragma unroll
                for (int r = 0; r < 4; ++r) {
                    v1[r] = f2bf(acc[i][j][r]     + b1);
                    v2[r] = f2bf(acc[i][j + 2][r] + b2);
                }
                const size_t off = ((size_t)(bb * NHEAD + head) * DHEAD + dim) * S_LEN + sb;
                *(bf16x4*)(vws + off)                        = v1;
                *(bf16x4*)(vws + off + (size_t)32 * S_LEN)   = v2;
            } else {
                // RoPE via angle recurrence: base sincos at s=sb, rotate by
                // inv_freq for r=1..3. 10 sincos per thread instead of 32.
                const float inv_freq = __expf(-(float)dim * 0.28782313662425572f);
                const float kscale = (which == 1) ? QKSCALE : 1.0f;
                bf16_t* outp = (which == 0) ? qws : kws;
                float sf, cf, sn, cs;
                __sincosf(inv_freq, &sf, &cf);
                __sincosf((float)sb * inv_freq, &sn, &cs);
#pragma unroll
                for (int r = 0; r < 4; ++r) {
                    const float x1 = acc[i][j][r]     + b1;
                    const float x2 = acc[i][j + 2][r] + b2;
                    const float csu = cs * kscale;
                    const float snu = sn * kscale;
                    const float o1 = x1 * csu - x2 * snu;
                    const float o2 = x2 * csu + x1 * snu;
                    const size_t off = ((size_t)(bb * NHEAD + head) * S_LEN + (sb + r)) * DHEAD + dim;
                    outp[off]      = f2bf(o1);
                    outp[off + 32] = f2bf(o2);
                    const float cs2 = cs * cf - sn * sf;   // rotate to s+1
                    sn = sn * cf + cs * sf;
                    cs = cs2;
                }
            }
        }
    }
}

// ---------------------------------------------------------------------------
// Kernel 2 (unchanged from r14, the measured-best config): flash attention,
// operand-swapped QK^T, no-max base-2 softmax, IN-LANE P (sigma k-order),
// V^T staged per block in LDS (slot-XOR swizzle, dbuf), raw lgkmcnt-only
// barrier per iter. (256,3) — (256,4) spills (r9). attn grid is already
// XCD-perfect: XCD = bh%8 pins each bh's K/V to one L2.
// ---------------------------------------------------------------------------
#define STK 72

__global__ __launch_bounds__(256, 3)
void attn_kernel(const bf16_t* __restrict__ qws, const bf16_t* __restrict__ kws,
                 const bf16_t* __restrict__ vtws, float* __restrict__ out)
{
    __shared__ bf16_t Ks[2][64 * STK]; // 2 x 9216 B  K [t][d], double-buffered
    __shared__ bf16_t Vs[2][64 * 64];  // 2 x 8192 B  V^T [d][t-slots], swizzled

    const int tid  = threadIdx.x;
    const int wave = tid >> 6;
    const int lane = tid & 63;
    const int l15  = lane & 15;
    const int quad = lane >> 4;
    const int bh   = blockIdx.x;          // 0..63  (XCD = bh % 8)
    const int qt   = blockIdx.y;          // 0..15
    const size_t baseS = (size_t)bh * S_LEN * DHEAD;   // q/k [s][d]; vt [d][s]
    const int q0 = qt * 128 + wave * 32;

    // Q fragments (B-operand: n=q on lane&15, k=d on quad*8+j), persistent.
    bf16x8 aq[2][2];
#pragma unroll
    for (int qsub = 0; qsub < 2; ++qsub)
#pragma unroll
        for (int kb = 0; kb < 2; ++kb)
            aq[qsub][kb] = *(const bf16x8*)(qws + baseS +
                (size_t)(q0 + qsub * 16 + l15) * DHEAD + kb * 32 + quad * 8);

    // staging coords (both K and V): thread covers row tid>>2, 2 x 16B.
    const int srow = tid >> 2;            // K: t row   V: d row
    const int scol = (tid & 3) * 8;       // elem base (+ jj*32)
    const bf16_t* kstage = kws  + baseS + (size_t)srow * DHEAD + scol;
    const bf16_t* vstage = vtws + baseS + (size_t)srow * S_LEN + scol;
    const int r15w = srow & 15;           // write-side swizzle key

    // Prologue: tile 0 -> Ks[0]/Vs[0]; tile 1 -> kreg/vreg; one barrier.
    uint4 kreg[2], vreg[2];
#pragma unroll
    for (int jj = 0; jj < 2; ++jj) {
        kreg[jj] = *(const uint4*)(kstage + jj * 32);
        vreg[jj] = *(const uint4*)(vstage + jj * 32);
    }
#pragma unroll
    for (int jj = 0; jj < 2; ++jj) {
        *(uint4*)(&Ks[0][0] + srow * STK + scol + jj * 32) = kreg[jj];
        const int s0 = (tid & 3) * 2 + jj * 8;
        *(uint2*)(&Vs[0][0] + srow * 64 + (((s0    ) ^ r15w) << 2)) =
            make_uint2(vreg[jj].x, vreg[jj].y);
        *(uint2*)(&Vs[0][0] + srow * 64 + (((s0 + 1) ^ r15w) << 2)) =
            make_uint2(vreg[jj].z, vreg[jj].w);
    }
#pragma unroll
    for (int jj = 0; jj < 2; ++jj) {
        kreg[jj] = *(const uint4*)(kstage + 64 * DHEAD + jj * 32);
        vreg[jj] = *(const uint4*)(vstage + 64       + jj * 32);
    }
    __syncthreads();

    float l_loc[2] = {0.f, 0.f};          // lane-local partial sums
    floatx4 o_acc[2][4];
#pragma unroll
    for (int qsub = 0; qsub < 2; ++qsub)
#pragma unroll
        for (int dt = 0; dt < 4; ++dt)
            o_acc[qsub][dt] = (floatx4){0.f, 0.f, 0.f, 0.f};

    for (int kt = 0; kt < 32; ++kt) {
        const int cur = kt & 1;

        // --- S^T = K Q^T : C row = t (quad*4+r), col = q (l15) -------------
        floatx4 st[2][4];
#pragma unroll
        for (int qsub = 0; qsub < 2; ++qsub)
#pragma unroll
            for (int mt = 0; mt < 4; ++mt)
                st[qsub][mt] = (floatx4){0.f, 0.f, 0.f, 0.f};
#pragma unroll
        for (int kb = 0; kb < 2; ++kb)
#pragma unroll
            for (int mt = 0; mt < 4; ++mt) {
                bf16x8 ak = *(const bf16x8*)(&Ks[cur][0] + (mt * 16 + l15) * STK + kb * 32 + quad * 8);
#pragma unroll
                for (int qsub = 0; qsub < 2; ++qsub)
                    st[qsub][mt] = __builtin_amdgcn_mfma_f32_16x16x32_bf16(
                        ak, aq[qsub][kb], st[qsub][mt], 0, 0, 0);
            }

        // --- V fragments from LDS (sigma k-order, swizzled) ----------------
        // elem j of bv[kb][dt] = V^T[dt*16+l15][kt*64 + kb*32 + quad*4
        //                                       + (j>>2)*16 + (j&3)]
        bf16x8 bv[2][4];
#pragma unroll
        for (int kb = 0; kb < 2; ++kb)
#pragma unroll
            for (int dt = 0; dt < 4; ++dt) {
                const bf16_t* vb = &Vs[cur][0] + (dt * 16 + l15) * 64;
                *(bf16x4*)(&bv[kb][dt]) =
                    *(const bf16x4*)(vb + (((kb * 8 + quad    ) ^ l15) << 2));
                *((bf16x4*)(&bv[kb][dt]) + 1) =
                    *(const bf16x4*)(vb + (((kb * 8 + quad + 4) ^ l15) << 2));
            }

        // --- stage tile kt+1 into other buffer; prefetch tile kt+2 ---------
        if (kt + 1 < 32) {
#pragma unroll
            for (int jj = 0; jj < 2; ++jj) {
                *(uint4*)(&Ks[cur ^ 1][0] + srow * STK + scol + jj * 32) = kreg[jj];
                const int s0 = (tid & 3) * 2 + jj * 8;
                *(uint2*)(&Vs[cur ^ 1][0] + srow * 64 + (((s0    ) ^ r15w) << 2)) =
                    make_uint2(vreg[jj].x, vreg[jj].y);
                *(uint2*)(&Vs[cur ^ 1][0] + srow * 64 + (((s0 + 1) ^ r15w) << 2)) =
                    make_uint2(vreg[jj].z, vreg[jj].w);
            }
            if (kt + 2 < 32) {
#pragma unroll
                for (int jj = 0; jj < 2; ++jj) {
                    kreg[jj] = *(const uint4*)(kstage + (size_t)(kt + 2) * 64 * DHEAD + jj * 32);
                    vreg[jj] = *(const uint4*)(vstage + (kt + 2) * 64 + jj * 32);
                }
            }
        }

        // --- softmax numerator p = 2^st, packed IN-LANE into PV A-frags ----
        // ap[qsub][kb] elem (mt&1)*4+r  <-  p[mt = kb*2 + (mt&1)][r]
        bf16x8 ap[2][2];
#pragma unroll
        for (int qsub = 0; qsub < 2; ++qsub) {
            float rs = 0.f;
#pragma unroll
            for (int mt = 0; mt < 4; ++mt) {
#pragma unroll
                for (int r = 0; r < 4; ++r) {
                    const float p = fexp2(st[qsub][mt][r]);
                    ap[qsub][mt >> 1][(mt & 1) * 4 + r] = f2bf(p);
                    rs += p;
                }
            }
            l_loc[qsub] += rs;
        }

        // --- O += P V (sigma-consistent on both operands) ------------------
#pragma unroll
        for (int kb = 0; kb < 2; ++kb)
#pragma unroll
            for (int qsub = 0; qsub < 2; ++qsub)
#pragma unroll
                for (int dt = 0; dt < 4; ++dt)
                    o_acc[qsub][dt] = __builtin_amdgcn_mfma_f32_16x16x32_bf16(
                        ap[qsub][kb], bv[kb][dt], o_acc[qsub][dt], 0, 0, 0);

        // raw barrier: LDS ops drained (writes visible, reads done -> WAR
        // closed); pending global prefetch loads stay in flight (register
        // targets; compiler waits vmcnt before their ds_write uses).
        if (kt + 1 < 32) {
            asm volatile("s_waitcnt lgkmcnt(0)" ::: "memory");
            __builtin_amdgcn_s_barrier();
        }
    }

    // reduce l across quads (linear sum -> order-free), once, after the loop
    float l_i[2];
#pragma unroll
    for (int qsub = 0; qsub < 2; ++qsub) {
        float rs = l_loc[qsub];
        rs += __shfl_xor(rs, 16, 64);
        rs += __shfl_xor(rs, 32, 64);
        l_i[qsub] = rs;
    }

    // normalize + store out[b][s][h*64+d] (fp32); l transposed via shfl
    const int bb = bh >> 4, hh = bh & 15;
#pragma unroll
    for (int qsub = 0; qsub < 2; ++qsub)
#pragma unroll
        for (int r = 0; r < 4; ++r) {
            const float lv  = __shfl(l_i[qsub], (lane & 48) | (quad * 4 + r), 64);
            const float inv = 1.0f / lv;
            const int s = q0 + qsub * 16 + quad * 4 + r;
            const size_t off0 = ((size_t)(bb * S_LEN + s)) * HD + hh * DHEAD;
#pragma unroll
            for (int dt = 0; dt < 4; ++dt)
                out[off0 + dt * 16 + l15] = o_acc[qsub][dt][r] * inv;
        }
}

extern "C" void kernel_launch(void* const* d_in, const int* in_sizes, int n_in,
                              void* d_out, int out_size, void* d_ws, size_t ws_size,
                              hipStream_t stream) {
    const float* X    = (const float*)d_in[0];   // (4,2048,1024) fp32
    const float* W    = (const float*)d_in[1];   // (3072,1024) fp32
    const float* bias = (const float*)d_in[2];   // (3072,) fp32
    float* out = (float*)d_out;                  // (4,2048,1024) fp32

    const size_t per = (size_t)B_SZ * NHEAD * S_LEN * DHEAD;   // 8.39M elems
    bf16_t* qws = (bf16_t*)d_ws;
    bf16_t* kws = qws + per;
    bf16_t* vws = kws + per;                     // holds V^T [b][h][d][s]

    // bf16 copies of X and W live in the out buffer as scratch (23.1 MB of
    // 33.5 MB); consumed by the GEMM, clobbered later by attn's real output.
    bf16_t* Xb = (bf16_t*)out;
    bf16_t* Wb = Xb + (size_t)NXELEM;

    cvt_kernel<<<dim3(4096), 256, 0, stream>>>(X, W, Xb, Wb);
    qkv_gemm_kernel<<<dim3(N3 / 128, M_ROWS / 128), 256, 0, stream>>>(
        Xb, Wb, bias, qws, kws, vws);
    attn_kernel<<<dim3(B_SZ * NHEAD, S_LEN / 128), 256, 0, stream>>>(
        qws, kws, vws, out);
}

// Round 16
// 240.115 us; speedup vs baseline: 1.0470x; 1.0470x over previous
//
#include <hip/hip_runtime.h>
#include <hip/hip_bf16.h>
#include <math.h>

// Problem constants (B=4, S=2048, Hd=1024, h=16, d=64). fp32 in/out per the
// reference; bf16 internally (MFMA) with fp32 accumulation.
#define B_SZ   4
#define S_LEN  2048
#define HD     1024
#define NHEAD  16
#define DHEAD  64
#define N3     3072          // 3*Hd
#define M_ROWS 8192          // B*S

typedef __bf16 bf16_t;
typedef __bf16 bf16x4 __attribute__((ext_vector_type(4)));
typedef __bf16 bf16x8 __attribute__((ext_vector_type(8)));
typedef float  floatx4 __attribute__((ext_vector_type(4)));

__device__ __forceinline__ float bf2f(bf16_t x) { return (float)x; }
__device__ __forceinline__ bf16_t f2bf(float f) { return (bf16_t)f; }  // RNE fptrunc
__device__ __forceinline__ float fexp2(float x) { return __builtin_amdgcn_exp2f(x); }

#define QKSCALE 0.1803368801111204f   // 0.125 * log2(e), folded into K in k1

__device__ __forceinline__ bf16x8 cvt8(const float4 lo, const float4 hi) {
    bf16x8 r;
    r[0] = (bf16_t)lo.x; r[1] = (bf16_t)lo.y; r[2] = (bf16_t)lo.z; r[3] = (bf16_t)lo.w;
    r[4] = (bf16_t)hi.x; r[5] = (bf16_t)hi.y; r[6] = (bf16_t)hi.z; r[7] = (bf16_t)hi.w;
    return r;
}

// async 16B global -> LDS (dest = wave-uniform base + lane*16)
__device__ __forceinline__ void gload_lds16(const bf16_t* g, bf16_t* l) {
    __builtin_amdgcn_global_load_lds(
        (const __attribute__((address_space(1))) void*)g,
        (__attribute__((address_space(3))) void*)l, 16, 0, 0);
}

// ---------------------------------------------------------------------------
// Kernel 0: one-shot fp32 -> bf16 convert of X and W (GEMM stages with
// global_load_lds, which can't convert dtypes). Scratch lives in the OUT
// buffer (23.1 MB <= 33.5 MB); out is only truly written by the attn kernel.
// ---------------------------------------------------------------------------
#define NXELEM (M_ROWS * HD)      // 8388608
#define NWELEM (N3 * HD)          // 3145728

__global__ __launch_bounds__(256)
void cvt_kernel(const float* __restrict__ X, const float* __restrict__ W,
                bf16_t* __restrict__ Xb, bf16_t* __restrict__ Wb)
{
    const size_t i = ((size_t)blockIdx.x * 256 + threadIdx.x) * 8;
    if (i < (size_t)NXELEM) {
        float4 lo = *(const float4*)(X + i);
        float4 hi = *(const float4*)(X + i + 4);
        *(bf16x8*)(Xb + i) = cvt8(lo, hi);
    }
    if (i < (size_t)NWELEM) {
        float4 lo = *(const float4*)(W + i);
        float4 hi = *(const float4*)(W + i + 4);
        *(bf16x8*)(Wb + i) = cvt8(lo, hi);
    }
}

// ---------------------------------------------------------------------------
// Kernel 1: bf16 GEMM qkv = Xb @ Wb^T + b. Counted-vmcnt pipeline
// (r10-verified): 3 LDS buffers, 2-deep prefetch, raw s_barrier +
// `s_waitcnt vmcnt(4) lgkmcnt(0)`. Epilogue sincos recurrence (r11).
// r15's XCD band swizzle reverted (null). Round-16 change: K and V are
// written in ATTN-READY layouts (same store count, different addresses):
//  * K^S: row s stores dim at granule (dim>>3)^(s&7) -> attn K-stage is a
//    LINEAR global_load_lds copy; b128 frag reads use the XOR granule.
//  * V^P: V^T row d stores t-group g (4 consec t) of each 64-t window at
//    16B-granule P(g)^(d&7), half h(g), P=(g>>3)*4+(g&3), h=(g>>2)&1 ->
//    attn V-frag = ONE b128 whose elem order is exactly the sigma k-order
//    of the in-lane P (elems 0-3: group kb*8+quad; 4-7: kb*8+quad+4).
// ---------------------------------------------------------------------------
__global__ __launch_bounds__(256, 3)
void qkv_gemm_kernel(const bf16_t* __restrict__ Xb, const bf16_t* __restrict__ Wb,
                     const float* __restrict__ bias,
                     bf16_t* __restrict__ qws, bf16_t* __restrict__ kws,
                     bf16_t* __restrict__ vws)
{
    __shared__ bf16_t As[3][128 * 32];   // 3 x 8 KB, [row][32] bf16, linear
    __shared__ bf16_t Bs[3][128 * 32];   // 3 x 8 KB

    const int tid  = threadIdx.x;
    const int wave = tid >> 6;
    const int lane = tid & 63;
    const int l15  = lane & 15;
    const int quad = lane >> 4;
    const int wm   = wave >> 1;
    const int wn   = wave & 1;
    const int m0   = blockIdx.y * 128;
    const int n0   = blockIdx.x * 128;

    const int rowL = wave * 32 + (lane >> 2);   // + t*16
    const int colL = (lane & 3) * 8;
    const bf16_t* gA = Xb + (size_t)(m0 + rowL) * HD + colL;
    const bf16_t* gB = Wb + (size_t)(n0 + rowL) * HD + colL;
    const int lofs = wave * 1024;               // elems; +512 for t=1

    floatx4 acc[4][4];
#pragma unroll
    for (int i = 0; i < 4; ++i)
#pragma unroll
        for (int j = 0; j < 4; ++j)
            acc[i][j] = (floatx4){0.f, 0.f, 0.f, 0.f};

    // prologue: stage tile 0 -> buf0, tile 1 -> buf1; wait own tile0
    // (vmcnt(4): only tile1's 4 may remain) then raw barrier.
    gload_lds16(gA,                &As[0][0] + lofs);
    gload_lds16(gA + 16 * HD,      &As[0][0] + lofs + 512);
    gload_lds16(gB,                &Bs[0][0] + lofs);
    gload_lds16(gB + 16 * HD,      &Bs[0][0] + lofs + 512);
    gload_lds16(gA + 32,           &As[1][0] + lofs);
    gload_lds16(gA + 32 + 16 * HD, &As[1][0] + lofs + 512);
    gload_lds16(gB + 32,           &Bs[1][0] + lofs);
    gload_lds16(gB + 32 + 16 * HD, &Bs[1][0] + lofs + 512);
    asm volatile("s_waitcnt vmcnt(4)" ::: "memory");
    __builtin_amdgcn_s_barrier();

    int cur = 0, nx2 = 2;                       // buf of tile kt / tile kt+2
    for (int kt = 0; kt < 32; ++kt) {
        // issue stage of tile kt+2 (2-deep): loads stay in flight across
        // this iteration's end-of-iter wait.
        if (kt + 2 < 32) {
            const int k2 = (kt + 2) * 32;
            gload_lds16(gA + k2,           &As[nx2][0] + lofs);
            gload_lds16(gA + k2 + 16 * HD, &As[nx2][0] + lofs + 512);
            gload_lds16(gB + k2,           &Bs[nx2][0] + lofs);
            gload_lds16(gB + k2 + 16 * HD, &Bs[nx2][0] + lofs + 512);
        }

        bf16x8 af[4], bfr[4];
#pragma unroll
        for (int t = 0; t < 4; ++t) {
            af[t]  = *(const bf16x8*)(&As[cur][0] + (wm * 64 + t * 16 + l15) * 32 + quad * 8);
            bfr[t] = *(const bf16x8*)(&Bs[cur][0] + (wn * 64 + t * 16 + l15) * 32 + quad * 8);
        }
#pragma unroll
        for (int i = 0; i < 4; ++i)
#pragma unroll
            for (int j = 0; j < 4; ++j)
                acc[i][j] = __builtin_amdgcn_mfma_f32_16x16x32_bf16(
                    af[i], bfr[j], acc[i][j], 0, 0, 0);

        // end-of-iter: own tile kt+1 loads done (vmcnt(4): tile kt+2's may
        // remain) + own ds_reads done (lgkmcnt(0)). Raw barrier: no drain.
        if (kt < 30) {
            asm volatile("s_waitcnt vmcnt(4) lgkmcnt(0)" ::: "memory");
            __builtin_amdgcn_s_barrier();
        } else if (kt == 30) {
            asm volatile("s_waitcnt vmcnt(0) lgkmcnt(0)" ::: "memory");
            __builtin_amdgcn_s_barrier();
        }
        cur = (cur == 2) ? 0 : cur + 1;
        nx2 = (nx2 == 2) ? 0 : nx2 + 1;
    }

    // Epilogue: bias + RoPE + scatter. C/D: col=lane&15, row=quad*4+reg.
#pragma unroll
    for (int i = 0; i < 4; ++i) {
        const int mrow_base = m0 + wm * 64 + i * 16 + quad * 4;
        const int bb = mrow_base >> 11;
        const int sb = mrow_base & (S_LEN - 1);
#pragma unroll
        for (int j = 0; j < 2; ++j) {
            const int n1 = n0 + wn * 64 + j * 16 + l15;    // dim in [0,32)
            const int n2 = n1 + 32;
            const float b1 = bias[n1];
            const float b2 = bias[n2];
            const int which = n1 >> 10;          // 0=q 1=k 2=v (block-uniform)
            const int hd    = n1 & 1023;
            const int head  = hd >> 6;
            const int dim   = hd & 63;           // < 32 by construction
            if (which == 2) {
                // V^P: no RoPE; pair-permuted + d-swizzled V^T (see header).
                bf16x4 v1, v2;
#pragma unroll
                for (int r = 0; r < 4; ++r) {
                    v1[r] = f2bf(acc[i][j][r]     + b1);
                    v2[r] = f2bf(acc[i][j + 2][r] + b2);
                }
                const int w   = sb >> 6;
                const int g   = (sb >> 2) & 15;
                const int P   = ((g >> 3) << 2) | (g & 3);
                const int h   = (g >> 2) & 1;
                const int pos = (((P ^ (dim & 7)) << 1) | h) << 2;  // elem off
                const size_t row1 = ((size_t)(bb * NHEAD + head) * DHEAD + dim) * S_LEN;
                *(bf16x4*)(vws + row1 + w * 64 + pos)                      = v1;
                *(bf16x4*)(vws + row1 + (size_t)32 * S_LEN + w * 64 + pos) = v2;
            } else if (which == 0) {
                // Q: plain [b][h][s][d] (attn reads q-frags directly).
                const float inv_freq = __expf(-(float)dim * 0.28782313662425572f);
                float sf, cf, sn, cs;
                __sincosf(inv_freq, &sf, &cf);
                __sincosf((float)sb * inv_freq, &sn, &cs);
#pragma unroll
                for (int r = 0; r < 4; ++r) {
                    const float x1 = acc[i][j][r]     + b1;
                    const float x2 = acc[i][j + 2][r] + b2;
                    const float o1 = x1 * cs - x2 * sn;
                    const float o2 = x2 * cs + x1 * sn;
                    const size_t off = ((size_t)(bb * NHEAD + head) * S_LEN + (sb + r)) * DHEAD + dim;
                    qws[off]      = f2bf(o1);
                    qws[off + 32] = f2bf(o2);
                    const float cs2 = cs * cf - sn * sf;   // rotate to s+1
                    sn = sn * cf + cs * sf;
                    cs = cs2;
                }
            } else {
                // K^S: QKSCALE folded; row s stores dim at granule
                // (dim>>3)^(s&7) (gload_lds-ready for attn).
                const float inv_freq = __expf(-(float)dim * 0.28782313662425572f);
                const int g1 = dim >> 3;             // 0..3 (dim < 32)
                const int d7 = dim & 7;
                float sf, cf, sn, cs;
                __sincosf(inv_freq, &sf, &cf);
                __sincosf((float)sb * inv_freq, &sn, &cs);
#pragma unroll
                for (int r = 0; r < 4; ++r) {
                    const float x1 = acc[i][j][r]     + b1;
                    const float x2 = acc[i][j + 2][r] + b2;
                    const float csu = cs * QKSCALE;
                    const float snu = sn * QKSCALE;
                    const float o1 = x1 * csu - x2 * snu;
                    const float o2 = x2 * csu + x1 * snu;
                    const int s    = sb + r;
                    const int skey = s & 7;
                    const size_t rowb = ((size_t)(bb * NHEAD + head) * S_LEN + s) * DHEAD;
                    kws[rowb + (((g1    ) ^ skey) << 3) + d7] = f2bf(o1);
                    kws[rowb + (((g1 + 4) ^ skey) << 3) + d7] = f2bf(o2);
                    const float cs2 = cs * cf - sn * sf;   // rotate to s+1
                    sn = sn * cf + cs * sf;
                    cs = cs2;
                }
            }
        }
    }
}

// ---------------------------------------------------------------------------
// Kernel 2: flash attention, operand-swapped QK^T, no-max base-2 softmax,
// IN-LANE P (sigma k-order).
// Round-16 change: DMA STAGING. r14 counters imply the attn wall is the
// CU-shared LDS pipe (~260cy/wave-iter: 30 ds ops incl. 6 staging writes +
// reg round-trip). K and V now arrive in attn-ready global layouts (K^S,
// V^P from k1), so staging is 4 global_load_lds16 per wave per iter
// (linear dest; swizzle baked into the global layout) — no ds_writes, no
// kreg/vreg, no staging VALU. V-frags are now ONE b128 each (was 2 b64).
// End-of-iter: vmcnt(0)+lgkmcnt(0) + raw barrier (DMA issued at iter top
// had the whole ~2000cy iter to land; only 8 loads in flight).
// LDS 32 KB. (256,3) — (256,4) spills (r9).
// ---------------------------------------------------------------------------
__global__ __launch_bounds__(256, 3)
void attn_kernel(const bf16_t* __restrict__ qws, const bf16_t* __restrict__ kws,
                 const bf16_t* __restrict__ vpws, float* __restrict__ out)
{
    __shared__ bf16_t Ks[2][64 * 64];  // 2 x 8 KB  K^S [t][granule-swz d]
    __shared__ bf16_t Vs[2][64 * 64];  // 2 x 8 KB  V^P [d][pair-perm t]

    const int tid  = threadIdx.x;
    const int wave = tid >> 6;
    const int lane = tid & 63;
    const int l15  = lane & 15;
    const int quad = lane >> 4;
    const int bh   = blockIdx.x;          // 0..63  (XCD = bh % 8)
    const int qt   = blockIdx.y;          // 0..15
    const size_t baseS = (size_t)bh * S_LEN * DHEAD;   // q/k [s][d]; vp [d][s']
    const int q0 = qt * 128 + wave * 32;

    // Q fragments (B-operand: n=q on lane&15, k=d on quad*8+j), persistent.
    bf16x8 aq[2][2];
#pragma unroll
    for (int qsub = 0; qsub < 2; ++qsub)
#pragma unroll
        for (int kb = 0; kb < 2; ++kb)
            aq[qsub][kb] = *(const bf16x8*)(qws + baseS +
                (size_t)(q0 + qsub * 16 + l15) * DHEAD + kb * 32 + quad * 8);

    // DMA staging: wave w covers rows w*16 + jj*8 + (lane>>3), 16B granule
    // lane&7 — linear in both global (layouts pre-swizzled by k1) and LDS.
    const int lrow8 = lane >> 3;          // 0..7
    const int lcol8 = (lane & 7) * 8;     // elem offset within 128B row
    const bf16_t* ksrc = kws  + baseS + (size_t)(wave * 16 + lrow8) * DHEAD + lcol8;
    const bf16_t* vsrc = vpws + baseS + (size_t)(wave * 16 + lrow8) * S_LEN + lcol8;
    const int ldst = wave * 1024;         // + jj*512 elems

    // Prologue: DMA tile 0 into buf 0; drain; barrier.
#pragma unroll
    for (int jj = 0; jj < 2; ++jj) {
        gload_lds16(ksrc + jj * 8 * DHEAD,          &Ks[0][0] + ldst + jj * 512);
        gload_lds16(vsrc + (size_t)jj * 8 * S_LEN,  &Vs[0][0] + ldst + jj * 512);
    }
    asm volatile("s_waitcnt vmcnt(0)" ::: "memory");
    __builtin_amdgcn_s_barrier();

    // per-kb frag granule offsets (elems), shared by K and V reads
    const int goff0 = ((quad     ^ (l15 & 7)) << 3);
    const int goff1 = (((4+quad) ^ (l15 & 7)) << 3);

    float l_loc[2] = {0.f, 0.f};          // lane-local partial sums
    floatx4 o_acc[2][4];
#pragma unroll
    for (int qsub = 0; qsub < 2; ++qsub)
#pragma unroll
        for (int dt = 0; dt < 4; ++dt)
            o_acc[qsub][dt] = (floatx4){0.f, 0.f, 0.f, 0.f};

    for (int kt = 0; kt < 32; ++kt) {
        const int cur = kt & 1;

        // --- DMA stage of tile kt+1 into other buffer (async) --------------
        if (kt + 1 < 32) {
            const size_t ko = (size_t)(kt + 1) * 64 * DHEAD;
            const int    vo = (kt + 1) * 64;
#pragma unroll
            for (int jj = 0; jj < 2; ++jj) {
                gload_lds16(ksrc + ko + jj * 8 * DHEAD,
                            &Ks[cur ^ 1][0] + ldst + jj * 512);
                gload_lds16(vsrc + vo + (size_t)jj * 8 * S_LEN,
                            &Vs[cur ^ 1][0] + ldst + jj * 512);
            }
        }

        // --- S^T = K Q^T : C row = t (quad*4+r), col = q (l15) -------------
        floatx4 st[2][4];
#pragma unroll
        for (int qsub = 0; qsub < 2; ++qsub)
#pragma unroll
            for (int mt = 0; mt < 4; ++mt)
                st[qsub][mt] = (floatx4){0.f, 0.f, 0.f, 0.f};
#pragma unroll
        for (int kb = 0; kb < 2; ++kb)
#pragma unroll
            for (int mt = 0; mt < 4; ++mt) {
                bf16x8 ak = *(const bf16x8*)(&Ks[cur][0] + (mt * 16 + l15) * 64 +
                                             (kb ? goff1 : goff0));
#pragma unroll
                for (int qsub = 0; qsub < 2; ++qsub)
                    st[qsub][mt] = __builtin_amdgcn_mfma_f32_16x16x32_bf16(
                        ak, aq[qsub][kb], st[qsub][mt], 0, 0, 0);
            }

        // --- V fragments: one b128 each, elem order = sigma k-order --------
        bf16x8 bv[2][4];
#pragma unroll
        for (int kb = 0; kb < 2; ++kb)
#pragma unroll
            for (int dt = 0; dt < 4; ++dt)
                bv[kb][dt] = *(const bf16x8*)(&Vs[cur][0] + (dt * 16 + l15) * 64 +
                                              (kb ? goff1 : goff0));

        // --- softmax numerator p = 2^st, packed IN-LANE into PV A-frags ----
        // ap[qsub][kb] elem (mt&1)*4+r  <-  p[mt = kb*2 + (mt&1)][r]
        bf16x8 ap[2][2];
#pragma unroll
        for (int qsub = 0; qsub < 2; ++qsub) {
            float rs = 0.f;
#pragma unroll
            for (int mt = 0; mt < 4; ++mt) {
#pragma unroll
                for (int r = 0; r < 4; ++r) {
                    const float p = fexp2(st[qsub][mt][r]);
                    ap[qsub][mt >> 1][(mt & 1) * 4 + r] = f2bf(p);
                    rs += p;
                }
            }
            l_loc[qsub] += rs;
        }

        // --- O += P V (sigma-consistent on both operands) ------------------
#pragma unroll
        for (int kb = 0; kb < 2; ++kb)
#pragma unroll
            for (int qsub = 0; qsub < 2; ++qsub)
#pragma unroll
                for (int dt = 0; dt < 4; ++dt)
                    o_acc[qsub][dt] = __builtin_amdgcn_mfma_f32_16x16x32_bf16(
                        ap[qsub][kb], bv[kb][dt], o_acc[qsub][dt], 0, 0, 0);

        // --- end-of-iter: DMA landed (vmcnt 0, issued a full iter ago) +
        // own ds_reads done (lgkm 0 -> next iter's DMA may overwrite buf) ---
        if (kt + 1 < 32) {
            asm volatile("s_waitcnt vmcnt(0) lgkmcnt(0)" ::: "memory");
            __builtin_amdgcn_s_barrier();
        }
    }

    // reduce l across quads (linear sum -> order-free), once, after the loop
    float l_i[2];
#pragma unroll
    for (int qsub = 0; qsub < 2; ++qsub) {
        float rs = l_loc[qsub];
        rs += __shfl_xor(rs, 16, 64);
        rs += __shfl_xor(rs, 32, 64);
        l_i[qsub] = rs;
    }

    // normalize + store out[b][s][h*64+d] (fp32); l transposed via shfl
    const int bb = bh >> 4, hh = bh & 15;
#pragma unroll
    for (int qsub = 0; qsub < 2; ++qsub)
#pragma unroll
        for (int r = 0; r < 4; ++r) {
            const float lv  = __shfl(l_i[qsub], (lane & 48) | (quad * 4 + r), 64);
            const float inv = 1.0f / lv;
            const int s = q0 + qsub * 16 + quad * 4 + r;
            const size_t off0 = ((size_t)(bb * S_LEN + s)) * HD + hh * DHEAD;
#pragma unroll
            for (int dt = 0; dt < 4; ++dt)
                out[off0 + dt * 16 + l15] = o_acc[qsub][dt][r] * inv;
        }
}

extern "C" void kernel_launch(void* const* d_in, const int* in_sizes, int n_in,
                              void* d_out, int out_size, void* d_ws, size_t ws_size,
                              hipStream_t stream) {
    const float* X    = (const float*)d_in[0];   // (4,2048,1024) fp32
    const float* W    = (const float*)d_in[1];   // (3072,1024) fp32
    const float* bias = (const float*)d_in[2];   // (3072,) fp32
    float* out = (float*)d_out;                  // (4,2048,1024) fp32

    const size_t per = (size_t)B_SZ * NHEAD * S_LEN * DHEAD;   // 8.39M elems
    bf16_t* qws = (bf16_t*)d_ws;
    bf16_t* kws = qws + per;                     // K^S (granule-swizzled)
    bf16_t* vws = kws + per;                     // V^P (pair-permuted V^T)

    // bf16 copies of X and W live in the out buffer as scratch (23.1 MB of
    // 33.5 MB); consumed by the GEMM, clobbered later by attn's real output.
    bf16_t* Xb = (bf16_t*)out;
    bf16_t* Wb = Xb + (size_t)NXELEM;

    cvt_kernel<<<dim3(4096), 256, 0, stream>>>(X, W, Xb, Wb);
    qkv_gemm_kernel<<<dim3(N3 / 128, M_ROWS / 128), 256, 0, stream>>>(
        Xb, Wb, bias, qws, kws, vws);
    attn_kernel<<<dim3(B_SZ * NHEAD, S_LEN / 128), 256, 0, stream>>>(
        qws, kws, vws, out);
}